// Round 6
// baseline (1080.216 us; speedup 1.0000x reference)
//
#include <hip/hip_runtime.h>

typedef __bf16 bf16x8 __attribute__((ext_vector_type(8)));
typedef float f32x4 __attribute__((ext_vector_type(4)));
using u16 = unsigned short;
using u32 = unsigned int;

#define B_   2
#define S_   2048
#define D_   1024
#define E_   8
#define HID_ 4096
#define M_   4096  // B_*S_

// ---------------- helpers ----------------
__device__ __forceinline__ u16 f2b_rne(float f) {
    unsigned u = __float_as_uint(f);
    u += 0x7fffu + ((u >> 16) & 1u);
    return (u16)(u >> 16);
}
__device__ __forceinline__ float b2f(u16 h) { return __uint_as_float(((unsigned)h) << 16); }
__device__ __forceinline__ void split2(float v, u16& h, u16& m) {
    h = f2b_rne(v); m = f2b_rne(v - b2f(h));
}
__device__ __forceinline__ void gld16(void* l, const void* g) {
    __builtin_amdgcn_global_load_lds((const __attribute__((address_space(1))) u32*)g,
                                     (__attribute__((address_space(3))) u32*)l, 16, 0, 0);
}

// ---------------- workspace layout (bytes) ----------------
static constexpr size_t OFF_WQKVT0 = 0;                                   // [1152][1024] bf16
static constexpr size_t OFF_WQKVT1 = OFF_WQKVT0 + (size_t)1152*1024*2;
static constexpr size_t OFF_WOT    = OFF_WQKVT1 + (size_t)1152*1024*2;    // [1024][1024] bf16 single
static constexpr size_t OFF_W1T    = OFF_WOT    + (size_t)1024*1024*2;    // [E][4096][1024]
static constexpr size_t OFF_W2T    = OFF_W1T    + (size_t)E_*HID_*D_*2;   // [E][1024][4096]
static constexpr size_t OFF_WOWG   = OFF_W2T    + (size_t)E_*HID_*D_*2;   // [1024][8] f32
static constexpr size_t OFF_HF32   = OFF_WOWG   + (size_t)1024*8*4;       // [4096][1024] f32 (h)
static constexpr size_t OFF_H0     = OFF_HF32   + (size_t)M_*D_*4;        // h split0
static constexpr size_t OFF_H1     = OFF_H0     + (size_t)M_*D_*2;        // h split1
static constexpr size_t OFF_H2     = OFF_H1     + (size_t)M_*D_*2;        // h2 bf16
static constexpr size_t OFF_CTL    = OFF_H2     + (size_t)M_*D_*2;        // 128 ints
static constexpr size_t OFF_TEXP   = OFF_CTL    + 512;
static constexpr size_t OFF_TGATE  = OFF_TEXP   + (size_t)M_*2*4;
static constexpr size_t OFF_R2T    = OFF_TGATE  + (size_t)M_*2*4;
static constexpr size_t OFF_T2R    = OFF_R2T    + (size_t)9216*4;
static constexpr size_t OFF_ZROW   = OFF_T2R    + (size_t)M_*2*4;         // 4096 B zeros
static constexpr size_t OFF_BIG    = OFF_ZROW   + 4096;
// attention phase inside BIG:
static constexpr size_t OFF_Q0     = OFF_BIG;                             // [4096][1024] bf16
static constexpr size_t OFF_Q1     = OFF_Q0   + (size_t)M_*D_*2;
static constexpr size_t OFF_KF0    = OFF_Q1   + (size_t)M_*D_*2;          // frag-major K split0: [2*128][2][512] u16
static constexpr size_t OFF_KF1    = OFF_KF0  + (size_t)2*128*2*512*2;
static constexpr size_t OFF_VF0    = OFF_KF1  + (size_t)2*128*2*512*2;    // frag-major V split0: [2*64][4][512] u16
static constexpr size_t OFF_VF1    = OFF_VF0  + (size_t)2*64*4*512*2;
static constexpr size_t OFF_OF32   = OFF_VF1  + (size_t)2*64*4*512*2;     // o fp32 [4096][1024]
static constexpr size_t OFF_AOBF   = OFF_OF32 + (size_t)M_*D_*4;          // o bf16 [4096][1024]
static constexpr size_t OFF_XF32   = OFF_Q0;                              // x2 fp32 (aliases Q0/Q1, safe)
// MoE phase aliases BIG:
static constexpr size_t OFF_TACT   = OFF_BIG;                             // [9216][4096] bf16
static constexpr size_t OFF_CONTR  = OFF_TACT + (size_t)9216*HID_*2;      // [9216][1024] bf16

// ---------------- transposes ----------------
__global__ __launch_bounds__(256) void transpose_split2_k(const float* __restrict__ in,
        u16* __restrict__ o0, u16* __restrict__ o1, int R, int C)
{
    __shared__ float tile[32][33];
    int tx = threadIdx.x & 31, ty = threadIdx.x >> 5;
    int c0 = blockIdx.x * 32, r0 = blockIdx.y * 32;
#pragma unroll
    for (int k = 0; k < 4; ++k)
        tile[ty + k*8][tx] = in[(size_t)(r0 + ty + k*8)*C + c0 + tx];
    __syncthreads();
#pragma unroll
    for (int k = 0; k < 4; ++k) {
        float v = tile[tx][ty + k*8];
        u16 h, m; split2(v, h, m);
        size_t idx = (size_t)(c0 + ty + k*8)*R + r0 + tx;
        o0[idx] = h; o1[idx] = m;
    }
}

__global__ __launch_bounds__(256) void transpose_k(const float* __restrict__ in,
                                                   u16* __restrict__ out, int R, int C)
{
    __shared__ u16 tile[32][33];
    int bz = blockIdx.z;
    in  += (size_t)bz * R * C;
    out += (size_t)bz * R * C;
    int tx = threadIdx.x & 31, ty = threadIdx.x >> 5;
    int c0 = blockIdx.x * 32, r0 = blockIdx.y * 32;
#pragma unroll
    for (int k = 0; k < 4; ++k)
        tile[ty + k*8][tx] = f2b_rne(in[(size_t)(r0 + ty + k*8)*C + c0 + tx]);
    __syncthreads();
#pragma unroll
    for (int k = 0; k < 4; ++k)
        out[(size_t)(c0 + ty + k*8)*R + r0 + tx] = tile[tx][ty + k*8];
}

// ---------------- WoWg = Wo @ Wg  (fp32, [1024][8]) ----------------
__global__ __launch_bounds__(64) void wowg_k(const float* __restrict__ Wo,
                                             const float* __restrict__ Wg,
                                             float* __restrict__ wowg)
{
    int i = blockIdx.x, lane = threadIdx.x;
    const float* wr = Wo + (size_t)i*1024;
    float acc[8] = {};
#pragma unroll
    for (int j = 0; j < 16; ++j) {
        int d = j*64 + lane;
        float wv = wr[d];
        const float* g = Wg + (size_t)d*8;
        float4 g0 = *(const float4*)g, g1 = *(const float4*)(g + 4);
        acc[0] += wv*g0.x; acc[1] += wv*g0.y; acc[2] += wv*g0.z; acc[3] += wv*g0.w;
        acc[4] += wv*g1.x; acc[5] += wv*g1.y; acc[6] += wv*g1.z; acc[7] += wv*g1.w;
    }
#pragma unroll
    for (int e = 0; e < 8; ++e)
#pragma unroll
        for (int o = 32; o; o >>= 1) acc[e] += __shfl_down(acc[e], o);
    if (lane == 0) {
#pragma unroll
        for (int e = 0; e < 8; ++e) wowg[i*8 + e] = acc[e];
    }
}

// ---------------- rmsnorm1: x -> h (f32 + 2-split) ----------------
__global__ __launch_bounds__(256) void rmsnorm1_k(const float* __restrict__ x,
                                                  float* __restrict__ hf,
                                                  u16* __restrict__ h0, u16* __restrict__ h1)
{
    int row = blockIdx.x, t = threadIdx.x;
    float4 v = ((const float4*)(x + (size_t)row*1024))[t];
    float ss = v.x*v.x + v.y*v.y + v.z*v.z + v.w*v.w;
#pragma unroll
    for (int o = 32; o; o >>= 1) ss += __shfl_down(ss, o);
    __shared__ float red[4];
    if ((t & 63) == 0) red[t >> 6] = ss;
    __syncthreads();
    float tot = red[0] + red[1] + red[2] + red[3];
    float sc = 32.0f / fmaxf(sqrtf(tot), 1e-12f);
    float vv[4] = {v.x*sc, v.y*sc, v.z*sc, v.w*sc};
    ((float4*)(hf + (size_t)row*1024))[t] = *(float4*)vv;
    u16 a0[4], a1[4];
#pragma unroll
    for (int j = 0; j < 4; ++j) split2(vv[j], a0[j], a1[j]);
    *(uint2*)(h0 + (size_t)row*1024 + t*4) = *(uint2*)a0;
    *(uint2*)(h1 + (size_t)row*1024 + t*4) = *(uint2*)a1;
}

// ---------------- QKV projection: 64x128 tile, A0/A1/B0/B1 staged once, 3 sweeps ----------------
// grid (64, 9); out cols 0..1023 = q (scaled), 1024..1151 = k|v frag-major scatter.
__global__ __launch_bounds__(256) void gemm_qkv(
    const u16* __restrict__ A0, const u16* __restrict__ A1,
    const u16* __restrict__ B0, const u16* __restrict__ B1,
    u16* __restrict__ q0, u16* __restrict__ q1,
    u16* __restrict__ kf0, u16* __restrict__ kf1,
    u16* __restrict__ vf0, u16* __restrict__ vf1)
{
    int rb = blockIdx.x, cb = blockIdx.y;
    __shared__ __attribute__((aligned(16))) char L[24576]; // As0 0 | As1 4K | Bs0 8K | Bs1 16K
    int t = threadIdx.x, w = t >> 6, lane = t & 63, r = lane & 15, g = lane >> 4;
    int wr = w >> 1, wc = w & 1;
    int arow = t >> 2, colA = (t & 3)*8;

    const char* a0c = (const char*)(A0 + (size_t)(rb*64  + arow)*1024 + colA);
    const char* a1c = (const char*)(A1 + (size_t)(rb*64  + arow)*1024 + colA);
    const char* b0c = (const char*)(B0 + (size_t)(cb*128 + arow)*1024 + colA);
    const char* b1c = (const char*)(B1 + (size_t)(cb*128 + arow)*1024 + colA);
    const size_t BH = (size_t)64*1024*2;  // +64 B-rows

    int aoff[2], boff[4];
#pragma unroll
    for (int i = 0; i < 2; ++i) aoff[i] = ((wr*32 + i*16 + r)*32 + g*8)*2;
#pragma unroll
    for (int i = 0; i < 4; ++i) boff[i] = ((wc*64 + i*16 + r)*32 + g*8)*2;

    f32x4 acc[2][4] = {};
    for (int kt = 0; kt < 32; ++kt) {
        __syncthreads();
        gld16(L +          t*16, a0c + kt*64);
        gld16(L + 4096  +  t*16, a1c + kt*64);
        gld16(L + 8192  +  t*16, b0c + kt*64);
        gld16(L + 12288 +  t*16, b0c + BH + kt*64);
        gld16(L + 16384 +  t*16, b1c + kt*64);
        gld16(L + 20480 +  t*16, b1c + BH + kt*64);
        __syncthreads();
        bf16x8 a0v[2], a1v[2], b0v[4], b1v[4];
#pragma unroll
        for (int i = 0; i < 2; ++i) { a0v[i] = *(const bf16x8*)(L + aoff[i]); a1v[i] = *(const bf16x8*)(L + 4096 + aoff[i]); }
#pragma unroll
        for (int i = 0; i < 4; ++i) { b0v[i] = *(const bf16x8*)(L + 8192 + boff[i]); b1v[i] = *(const bf16x8*)(L + 16384 + boff[i]); }
#pragma unroll
        for (int mi = 0; mi < 2; ++mi)
#pragma unroll
            for (int ni = 0; ni < 4; ++ni) {
                acc[mi][ni] = __builtin_amdgcn_mfma_f32_16x16x32_bf16(a0v[mi], b0v[ni], acc[mi][ni], 0, 0, 0);
                acc[mi][ni] = __builtin_amdgcn_mfma_f32_16x16x32_bf16(a0v[mi], b1v[ni], acc[mi][ni], 0, 0, 0);
                acc[mi][ni] = __builtin_amdgcn_mfma_f32_16x16x32_bf16(a1v[mi], b0v[ni], acc[mi][ni], 0, 0, 0);
            }
    }

#pragma unroll
    for (int mi = 0; mi < 2; ++mi)
#pragma unroll
        for (int ni = 0; ni < 4; ++ni) {
            int row0 = rb*64 + wr*32 + mi*16 + g*4;
            int col  = cb*128 + wc*64 + ni*16 + r;
#pragma unroll
            for (int reg = 0; reg < 4; ++reg) {
                float val = acc[mi][ni][reg];
                int rr = row0 + reg;
                if (col < 1024) {           // q, pre-scaled by 1/8
                    u16 hh, mm; split2(val * 0.125f, hh, mm);
                    size_t idx = (size_t)rr*1024 + col;
                    q0[idx] = hh; q1[idx] = mm;
                } else {
                    int c = col - 1024;     // 0..127: k (0-63) | v (64-127)
                    u16 hh, mm; split2(val, hh, mm);
                    int bb = rr >> 11, kv = rr & 2047;
                    if (c < 64) {           // K' [bb*128+ntg][kc][gg*16+r2][j]
                        int ntg = kv >> 4, r2 = kv & 15, kc = c >> 5, gg = (c >> 3) & 3, j = c & 7;
                        size_t off = ((((size_t)bb*128 + ntg)*2 + kc)*64 + gg*16 + r2)*8 + j;
                        kf0[off] = hh; kf1[off] = mm;
                    } else {                // V' [bb*64+kvc][ntg][gg*16+r2][j]
                        int d = c - 64;
                        int ntg = d >> 4, r2 = d & 15, kvc = kv >> 5, gg = (kv >> 3) & 3, j = kv & 7;
                        size_t off = ((((size_t)bb*64 + kvc)*4 + ntg)*64 + gg*16 + r2)*8 + j;
                        vf0[off] = hh; vf1[off] = mm;
                    }
                }
            }
        }
}

// ---------------- flash attention (MQA), 2-split, 8 warps x 16 q-rows ----------------
// grid (16 q-tiles of 128, 16 heads, 2 batch); 512 thr; KVBLK=64; K/V staged once per tile.
__global__ __launch_bounds__(512) void attn_k(
    const u16* __restrict__ q0, const u16* __restrict__ q1,
    const u16* __restrict__ kfr0, const u16* __restrict__ kfr1,
    const u16* __restrict__ vfr0, const u16* __restrict__ vfr1,
    float* __restrict__ of32, u16* __restrict__ obf)
{
    int qt = blockIdx.x, h = blockIdx.y, b = blockIdx.z;
    int t = threadIdx.x, w = t >> 6, lane = t & 63, r = lane & 15, g = lane >> 4;
    __shared__ __attribute__((aligned(16))) char smem[49152];
    char* plw = smem + 32768 + w*2048;   // per-warp P buffer [16][64] u16, XOR-swizzled

    const char* K0c = (const char*)kfr0;
    const char* K1c = (const char*)kfr1;
    const char* V0c = (const char*)vfr0;
    const char* V1c = (const char*)vfr1;

    int qrow = b*2048 + qt*128 + w*16 + r;
    bf16x8 qf0[2], qf1[2];
#pragma unroll
    for (int kc = 0; kc < 2; ++kc) {
        size_t qi = (size_t)qrow*1024 + h*64 + kc*32 + g*8;
        qf0[kc] = *(const bf16x8*)(q0 + qi);
        qf1[kc] = *(const bf16x8*)(q1 + qi);
    }

    f32x4 accO[4] = {};
    float mrun[4], lrun[4];
#pragma unroll
    for (int reg = 0; reg < 4; ++reg) { mrun[reg] = -1e30f; lrun[reg] = 0.f; }

    for (int kt = 0; kt < 32; ++kt) {
        __syncthreads();
        {   // stage K (2 splits) + V (2 splits), 8KB each, 512 threads x 16B x 4
            size_t kb = ((size_t)(b*128 + kt*4))*2048;
            size_t vb = ((size_t)(b*64  + kt*2))*4096;
            gld16(smem +          t*16, K0c + kb + t*16);
            gld16(smem + 8192  +  t*16, K1c + kb + t*16);
            gld16(smem + 16384 +  t*16, V0c + vb + t*16);
            gld16(smem + 24576 +  t*16, V1c + vb + t*16);
        }
        __syncthreads();

        // QK^T: 2-split, 3 products
        f32x4 s[4] = {};
#pragma unroll
        for (int nt = 0; nt < 4; ++nt)
#pragma unroll
            for (int kc = 0; kc < 2; ++kc) {
                bf16x8 kf0 = *(const bf16x8*)(smem + (nt*2 + kc)*1024 + lane*16);
                bf16x8 kf1 = *(const bf16x8*)(smem + 8192 + (nt*2 + kc)*1024 + lane*16);
                s[nt] = __builtin_amdgcn_mfma_f32_16x16x32_bf16(qf0[kc], kf0, s[nt], 0, 0, 0);
                s[nt] = __builtin_amdgcn_mfma_f32_16x16x32_bf16(qf0[kc], kf1, s[nt], 0, 0, 0);
                s[nt] = __builtin_amdgcn_mfma_f32_16x16x32_bf16(qf1[kc], kf0, s[nt], 0, 0, 0);
            }

        // online softmax (per q-row = (g, reg); kv spread over r-lanes)
#pragma unroll
        for (int reg = 0; reg < 4; ++reg) {
            float mx = fmaxf(fmaxf(s[0][reg], s[1][reg]), fmaxf(s[2][reg], s[3][reg]));
#pragma unroll
            for (int d = 1; d < 16; d <<= 1) mx = fmaxf(mx, __shfl_xor(mx, d));
            float mn = fmaxf(mrun[reg], mx);
            float alpha = __expf(mrun[reg] - mn);
            float ls = 0.f;
#pragma unroll
            for (int nt = 0; nt < 4; ++nt) {
                float pv = __expf(s[nt][reg] - mn);
                s[nt][reg] = pv; ls += pv;
            }
#pragma unroll
            for (int d = 1; d < 16; d <<= 1) ls += __shfl_xor(ls, d);
            lrun[reg] = lrun[reg]*alpha + ls;
            mrun[reg] = mn;
#pragma unroll
            for (int nt = 0; nt < 4; ++nt) accO[nt][reg] *= alpha;
        }

        // PV: P 2-split over 2 phases through per-warp swizzled LDS
#pragma unroll
        for (int ps = 0; ps < 2; ++ps) {
#pragma unroll
            for (int nt = 0; nt < 4; ++nt)
#pragma unroll
                for (int reg = 0; reg < 4; ++reg) {
                    float pv = s[nt][reg];
                    u16 hh = f2b_rne(pv);
                    if (ps) hh = f2b_rne(pv - b2f(hh));
                    int gr = g*4 + reg;
                    int off = (gr*128 + (nt*16 + r)*2) ^ ((gr & 7) << 4);
                    *(u16*)(plw + off) = hh;
                }
#pragma unroll
            for (int kc = 0; kc < 2; ++kc) {
                int po = (r*128 + kc*64 + g*16) ^ ((r & 7) << 4);
                bf16x8 pf = *(const bf16x8*)(plw + po);
#pragma unroll
                for (int nt = 0; nt < 4; ++nt) {
                    bf16x8 vf0 = *(const bf16x8*)(smem + 16384 + (kc*4 + nt)*1024 + lane*16);
                    accO[nt] = __builtin_amdgcn_mfma_f32_16x16x32_bf16(pf, vf0, accO[nt], 0, 0, 0);
                    if (ps == 0) {
                        bf16x8 vf1 = *(const bf16x8*)(smem + 24576 + (kc*4 + nt)*1024 + lane*16);
                        accO[nt] = __builtin_amdgcn_mfma_f32_16x16x32_bf16(pf, vf1, accO[nt], 0, 0, 0);
                    }
                }
            }
        }
    }

#pragma unroll
    for (int nt = 0; nt < 4; ++nt)
#pragma unroll
        for (int reg = 0; reg < 4; ++reg) {
            float o = accO[nt][reg] / lrun[reg];
            int row = b*2048 + qt*128 + w*16 + g*4 + reg;
            size_t idx = (size_t)row*1024 + h*64 + nt*16 + r;
            of32[idx] = o;
            obf[idx] = f2b_rne(o);
        }
}

// ---------------- single-bf16 128x128 GEMM (gld16 staging) ----------------
// EP: 0 = fp32 out (val + addsrc)   1 = gelu -> bf16   2 = plain bf16
template<int EP, bool MOE, bool INDIR>
__global__ __launch_bounds__(256) void gemm1(
    const u16* __restrict__ Abase, const u16* __restrict__ Bbase,
    u16* __restrict__ outb, float* __restrict__ outf, const float* __restrict__ addsrc,
    const int* __restrict__ r2t, const int* __restrict__ ctl, const u16* __restrict__ zrow,
    int K, int N)
{
    int rb = blockIdx.x, cb = blockIdx.y;
    if (MOE) { if (rb*128 >= ctl[16]) return; }
    const u16* Bt = Bbase;
    if (MOE) Bt += (size_t)ctl[32 + rb] * N * K;

    __shared__ __attribute__((aligned(16))) u16 As[4096];
    __shared__ __attribute__((aligned(16))) u16 Bs[4096];
    int t = threadIdx.x, w = t >> 6, lane = t & 63, r = lane & 15, g = lane >> 4;
    int wr = w >> 1, wc = w & 1;
    int arow0 = t >> 2, colA = (t & 3)*8;

    const char *gA0c, *gA1c;
    if (INDIR) {
        int tk0 = r2t[rb*128 + arow0];
        int tk1 = r2t[rb*128 + 64 + arow0];
        gA0c = (const char*)((tk0 < 0 ? zrow : Abase + (size_t)tk0*K) + colA);
        gA1c = (const char*)((tk1 < 0 ? zrow : Abase + (size_t)tk1*K) + colA);
    } else {
        gA0c = (const char*)(Abase + (size_t)(rb*128 + arow0)*K + colA);
        gA1c = (const char*)(Abase + (size_t)(rb*128 + 64 + arow0)*K + colA);
    }
    const char* gB0c = (const char*)(Bt + (size_t)(cb*128 + arow0)*K + colA);
    const char* gB1c = (const char*)(Bt + (size_t)(cb*128 + 64 + arow0)*K + colA);

    int aoff[4], boff[4];
#pragma unroll
    for (int i = 0; i < 4; ++i) {
        aoff[i] = ((wr*64 + i*16 + r)*32 + g*8)*2;
        boff[i] = ((wc*64 + i*16 + r)*32 + g*8)*2;
    }
    f32x4 acc[4][4] = {};
    int nk = K >> 5;
    for (int kt = 0; kt < nk; ++kt) {
        __syncthreads();
        gld16((char*)As + t*16,        gA0c + kt*64);
        gld16((char*)As + 4096 + t*16, gA1c + kt*64);
        gld16((char*)Bs + t*16,        gB0c + kt*64);
        gld16((char*)Bs + 4096 + t*16, gB1c + kt*64);
        __syncthreads();
        bf16x8 av[4], bv[4];
#pragma unroll
        for (int i = 0; i < 4; ++i) av[i] = *(const bf16x8*)((char*)As + aoff[i]);
#pragma unroll
        for (int i = 0; i < 4; ++i) bv[i] = *(const bf16x8*)((char*)Bs + boff[i]);
#pragma unroll
        for (int mi = 0; mi < 4; ++mi)
#pragma unroll
            for (int ni = 0; ni < 4; ++ni)
                acc[mi][ni] = __builtin_amdgcn_mfma_f32_16x16x32_bf16(av[mi], bv[ni], acc[mi][ni], 0, 0, 0);
    }

    int bm = rb*128, bn = cb*128;
#pragma unroll
    for (int mi = 0; mi < 4; ++mi)
#pragma unroll
        for (int ni = 0; ni < 4; ++ni) {
            int row0 = bm + wr*64 + mi*16 + g*4;
            int col  = bn + wc*64 + ni*16 + r;
#pragma unroll
            for (int reg = 0; reg < 4; ++reg) {
                float val = acc[mi][ni][reg];
                int rr = row0 + reg;
                size_t idx = (size_t)rr*N + col;
                if (EP == 0) {
                    outf[idx] = val + addsrc[idx];
                } else if (EP == 1) {
                    float u  = 1.5957691216f * (val + 0.044715f*val*val*val);
                    outb[idx] = f2b_rne(val / (1.0f + __expf(-u)));
                } else {
                    outb[idx] = f2b_rne(val);
                }
            }
        }
}

// ---------------- MoE GEMM2: 64x128 tile (K=4096, N=1024), denser grid ----------------
__global__ __launch_bounds__(256) void gemm_moe2(
    const u16* __restrict__ Abase, const u16* __restrict__ Bbase,
    u16* __restrict__ outb, const int* __restrict__ ctl)
{
    int rb = blockIdx.x, cb = blockIdx.y;
    if (rb*64 >= ctl[16]) return;
    const u16* Bt = Bbase + (size_t)ctl[32 + (rb >> 1)] * (size_t)1024 * 4096;

    __shared__ __attribute__((aligned(16))) char L[12288]; // As 4K | Bs 8K
    int t = threadIdx.x, w = t >> 6, lane = t & 63, r = lane & 15, g = lane >> 4;
    int wr = w >> 1, wc = w & 1;
    int arow = t >> 2, colA = (t & 3)*8;

    const char* aC = (const char*)(Abase + (size_t)(rb*64  + arow)*4096 + colA);
    const char* bC = (const char*)(Bt    + (size_t)(cb*128 + arow)*4096 + colA);
    const size_t BH = (size_t)64*4096*2;

    int aoff[2], boff[4];
#pragma unroll
    for (int i = 0; i < 2; ++i) aoff[i] = ((wr*32 + i*16 + r)*32 + g*8)*2;
#pragma unroll
    for (int i = 0; i < 4; ++i) boff[i] = ((wc*64 + i*16 + r)*32 + g*8)*2;

    f32x4 acc[2][4] = {};
    for (int kt = 0; kt < 128; ++kt) {
        __syncthreads();
        gld16(L +         t*16, aC + kt*64);
        gld16(L + 4096 +  t*16, bC + kt*64);
        gld16(L + 8192 +  t*16, bC + BH + kt*64);
        __syncthreads();
        bf16x8 av[2], bv[4];
#pragma unroll
        for (int i = 0; i < 2; ++i) av[i] = *(const bf16x8*)(L + aoff[i]);
#pragma unroll
        for (int i = 0; i < 4; ++i) bv[i] = *(const bf16x8*)(L + 4096 + boff[i]);
#pragma unroll
        for (int mi = 0; mi < 2; ++mi)
#pragma unroll
            for (int ni = 0; ni < 4; ++ni)
                acc[mi][ni] = __builtin_amdgcn_mfma_f32_16x16x32_bf16(av[mi], bv[ni], acc[mi][ni], 0, 0, 0);
    }

#pragma unroll
    for (int mi = 0; mi < 2; ++mi)
#pragma unroll
        for (int ni = 0; ni < 4; ++ni) {
            int row0 = rb*64 + wr*32 + mi*16 + g*4;
            int col  = cb*128 + wc*64 + ni*16 + r;
#pragma unroll
            for (int reg = 0; reg < 4; ++reg)
                outb[(size_t)(row0 + reg)*1024 + col] = f2b_rne(acc[mi][ni][reg]);
        }
}

// ---------------- fused rmsnorm2 + exact-fp32 top-2 gating (4 tokens/block) ----------------
__global__ __launch_bounds__(256) void gate_k(const float* __restrict__ x2,
                                             const float* __restrict__ hrow,
                                             const float* __restrict__ orow,
                                             const float* __restrict__ Wg,
                                             const float* __restrict__ wowg,
                                             u16* __restrict__ h2,
                                             int* __restrict__ texp, float* __restrict__ tgate,
                                             int* __restrict__ ctl)
{
    int tkn = blockIdx.x*4 + (threadIdx.x >> 6);
    int lane = threadIdx.x & 63;
    const float* xr  = x2   + (size_t)tkn*1024;
    const float* hr  = hrow + (size_t)tkn*1024;
    const float* orp = orow + (size_t)tkn*1024;
    float xv[16];
    float ss = 0.f;
    float acc[8] = {};
#pragma unroll
    for (int j = 0; j < 16; ++j) {
        int d = j*64 + lane;
        float xf = xr[d]; xv[j] = xf; ss += xf*xf;
        float hf = hr[d], of = orp[d];
        const float* wg = Wg + (size_t)d*8;
        const float* wo = wowg + (size_t)d*8;
        float4 a0 = *(const float4*)wg, a1 = *(const float4*)(wg + 4);
        float4 b0 = *(const float4*)wo, b1 = *(const float4*)(wo + 4);
        acc[0] += hf*a0.x + of*b0.x; acc[1] += hf*a0.y + of*b0.y;
        acc[2] += hf*a0.z + of*b0.z; acc[3] += hf*a0.w + of*b0.w;
        acc[4] += hf*a1.x + of*b1.x; acc[5] += hf*a1.y + of*b1.y;
        acc[6] += hf*a1.z + of*b1.z; acc[7] += hf*a1.w + of*b1.w;
    }
#pragma unroll
    for (int o = 32; o; o >>= 1) ss += __shfl_down(ss, o);
    ss = __shfl(ss, 0);
    float sc = 32.0f / fmaxf(sqrtf(ss), 1e-12f);
#pragma unroll
    for (int j = 0; j < 16; ++j)
        h2[(size_t)tkn*1024 + j*64 + lane] = f2b_rne(xv[j]*sc);
#pragma unroll
    for (int e = 0; e < 8; ++e)
#pragma unroll
        for (int o = 32; o; o >>= 1) acc[e] += __shfl_down(acc[e], o);
    if (lane == 0) {
        float lg[8];
#pragma unroll
        for (int e = 0; e < 8; ++e) lg[e] = acc[e]*sc;
        int i0 = 0; float v0 = lg[0];
#pragma unroll
        for (int e = 1; e < 8; ++e) if (lg[e] > v0) { v0 = lg[e]; i0 = e; }
        int i1 = -1; float v1 = -1e30f;
#pragma unroll
        for (int e = 0; e < 8; ++e) if (e != i0 && lg[e] > v1) { v1 = lg[e]; i1 = e; }
        float g0 = 1.0f / (1.0f + __expf(v1 - v0));
        texp[tkn*2] = i0; texp[tkn*2+1] = i1;
        tgate[tkn*2] = g0; tgate[tkn*2+1] = 1.0f - g0;
        atomicAdd(&ctl[i0], 1); atomicAdd(&ctl[i1], 1);
    }
}

// ---------------- MoE plan / assign ----------------
__global__ void plan_k(int* ctl, int* r2t)
{
    if (threadIdx.x == 0) {
        int off = 0;
        for (int e = 0; e < 8; ++e) {
            int c = ctl[e];
            ctl[8 + e] = off;
            int p = (c + 127) & ~127;
            int rb0 = off >> 7, nrbe = p >> 7;
            for (int i = 0; i < nrbe; ++i) ctl[32 + rb0 + i] = e;
            off += p;
        }
        ctl[16] = off; ctl[17] = off >> 7;
    }
    __syncthreads();
    for (int i = threadIdx.x; i < 9216; i += blockDim.x) r2t[i] = -1;
}

__global__ __launch_bounds__(256) void assign_k(const int* __restrict__ texp, int* ctl,
                                                int* __restrict__ r2t, int* __restrict__ t2r)
{
    int tkn = blockIdx.x*256 + threadIdx.x;
    if (tkn >= M_) return;
#pragma unroll
    for (int kk = 0; kk < 2; ++kk) {
        int e = texp[tkn*2 + kk];
        int pos = atomicAdd(&ctl[8 + e], 1);
        r2t[pos] = tkn;
        t2r[tkn*2 + kk] = pos;
    }
}

// ---------------- final combine ----------------
__global__ __launch_bounds__(256) void combine_k(const float* __restrict__ xin,
                                                 const u16* __restrict__ contrib,
                                                 const int* __restrict__ t2r,
                                                 const float* __restrict__ tgate,
                                                 float* __restrict__ out)
{
    int tkn = blockIdx.x;
    int c = threadIdx.x*4;
    int r0 = t2r[tkn*2], r1 = t2r[tkn*2+1];
    float g0 = tgate[tkn*2], g1 = tgate[tkn*2+1];
    float4 sk = *(const float4*)(xin + (size_t)tkn*1024 + c);
    const u16* c0p = contrib + (size_t)r0*1024 + c;
    const u16* c1p = contrib + (size_t)r1*1024 + c;
    float4 o;
    o.x = sk.x + g0*b2f(c0p[0]) + g1*b2f(c1p[0]);
    o.y = sk.y + g0*b2f(c0p[1]) + g1*b2f(c1p[1]);
    o.z = sk.z + g0*b2f(c0p[2]) + g1*b2f(c1p[2]);
    o.w = sk.w + g0*b2f(c0p[3]) + g1*b2f(c1p[3]);
    *(float4*)(out + (size_t)tkn*1024 + c) = o;
}

extern "C" void kernel_launch(void* const* d_in, const int* in_sizes, int n_in,
                              void* d_out, int out_size, void* d_ws, size_t ws_size,
                              hipStream_t stream)
{
    const float* x  = (const float*)d_in[0];
    const float* Wq = (const float*)d_in[1];
    const float* Wk = (const float*)d_in[2];
    const float* Wv = (const float*)d_in[3];
    const float* Wo = (const float*)d_in[4];
    const float* Wg = (const float*)d_in[5];
    const float* W1 = (const float*)d_in[6];
    const float* W2 = (const float*)d_in[7];
    float* out = (float*)d_out;

    char* ws = (char*)d_ws;
    auto U = [&](size_t off) { return (u16*)(ws + off); };
    auto F = [&](size_t off) { return (float*)(ws + off); };
    int*   CTL  = (int*)(ws + OFF_CTL);
    int*   TEXP = (int*)(ws + OFF_TEXP);
    float* TGATE= (float*)(ws + OFF_TGATE);
    int*   R2T  = (int*)(ws + OFF_R2T);
    int*   T2R  = (int*)(ws + OFF_T2R);

    hipMemsetAsync(ws + OFF_CTL,  0, 512,  stream);
    hipMemsetAsync(ws + OFF_ZROW, 0, 4096, stream);

    dim3 tb(256);
    // weights: QKV merged B^T [1152][1024] 2-split; Wo single; experts single
    transpose_split2_k<<<dim3(32, 32), tb, 0, stream>>>(Wq, U(OFF_WQKVT0), U(OFF_WQKVT1), 1024, 1024);
    transpose_split2_k<<<dim3(2, 32),  tb, 0, stream>>>(Wk, U(OFF_WQKVT0) + (size_t)1024*1024, U(OFF_WQKVT1) + (size_t)1024*1024, 1024, 64);
    transpose_split2_k<<<dim3(2, 32),  tb, 0, stream>>>(Wv, U(OFF_WQKVT0) + (size_t)1088*1024, U(OFF_WQKVT1) + (size_t)1088*1024, 1024, 64);
    transpose_k<<<dim3(32, 32, 1), tb, 0, stream>>>(Wo, U(OFF_WOT), 1024, 1024);
    transpose_k<<<dim3(128, 32, 8), tb, 0, stream>>>(W1, U(OFF_W1T), 1024, 4096);
    transpose_k<<<dim3(32, 128, 8), tb, 0, stream>>>(W2, U(OFF_W2T), 4096, 1024);
    wowg_k<<<1024, 64, 0, stream>>>(Wo, Wg, F(OFF_WOWG));

    rmsnorm1_k<<<M_, 256, 0, stream>>>(x, F(OFF_HF32), U(OFF_H0), U(OFF_H1));

    // QKV projection (q row-major 2-split; k/v fragment-major 2-split)
    gemm_qkv<<<dim3(64, 9), tb, 0, stream>>>(U(OFF_H0), U(OFF_H1),
        U(OFF_WQKVT0), U(OFF_WQKVT1),
        U(OFF_Q0), U(OFF_Q1), U(OFF_KF0), U(OFF_KF1), U(OFF_VF0), U(OFF_VF1));

    attn_k<<<dim3(16, 16, 2), dim3(512), 0, stream>>>(U(OFF_Q0), U(OFF_Q1),
        U(OFF_KF0), U(OFF_KF1), U(OFF_VF0), U(OFF_VF1), F(OFF_OF32), U(OFF_AOBF));

    // x2 = o @ Wo + h  (single-bf16 GEMM, fp32 out; XF32 aliases Q0/Q1 which are dead)
    gemm1<0, false, false><<<dim3(32, 8), tb, 0, stream>>>(U(OFF_AOBF), U(OFF_WOT),
        nullptr, F(OFF_XF32), F(OFF_HF32), nullptr, nullptr, nullptr, 1024, 1024);

    // rmsnorm2 + exact fp32 logits (h@Wg + o@WoWg) + top-2 gate
    gate_k<<<1024, 256, 0, stream>>>(F(OFF_XF32), F(OFF_HF32), F(OFF_OF32), Wg, F(OFF_WOWG),
        U(OFF_H2), TEXP, TGATE, CTL);
    plan_k<<<1, 256, 0, stream>>>(CTL, R2T);
    assign_k<<<16, 256, 0, stream>>>(TEXP, CTL, R2T, T2R);

    // expert GEMMs (top-2 sparse, single bf16)
    gemm1<1, true, true ><<<dim3(72, 32), tb, 0, stream>>>(U(OFF_H2), U(OFF_W1T),
        U(OFF_TACT), nullptr, nullptr, R2T, CTL, U(OFF_ZROW), 1024, 4096);
    gemm_moe2<<<dim3(144, 8), tb, 0, stream>>>(U(OFF_TACT), U(OFF_W2T), U(OFF_CONTR), CTL);

    combine_k<<<M_, 256, 0, stream>>>(x, U(OFF_CONTR), T2R, TGATE, out);
}

// Round 10
// 1055.527 us; speedup vs baseline: 1.0234x; 1.0234x over previous
//
#include <hip/hip_runtime.h>

typedef __bf16 bf16x8 __attribute__((ext_vector_type(8)));
typedef float f32x4 __attribute__((ext_vector_type(4)));
using u16 = unsigned short;
using u32 = unsigned int;

#define B_   2
#define S_   2048
#define D_   1024
#define E_   8
#define HID_ 4096
#define M_   4096  // B_*S_

// ---------------- helpers ----------------
__device__ __forceinline__ u16 f2b_rne(float f) {
    unsigned u = __float_as_uint(f);
    u += 0x7fffu + ((u >> 16) & 1u);
    return (u16)(u >> 16);
}
__device__ __forceinline__ float b2f(u16 h) { return __uint_as_float(((unsigned)h) << 16); }
__device__ __forceinline__ void split2(float v, u16& h, u16& m) {
    h = f2b_rne(v); m = f2b_rne(v - b2f(h));
}
__device__ __forceinline__ void gld16(void* l, const void* g) {
    __builtin_amdgcn_global_load_lds((const __attribute__((address_space(1))) u32*)g,
                                     (__attribute__((address_space(3))) u32*)l, 16, 0, 0);
}

// ---------------- workspace layout (bytes) ----------------
static constexpr size_t OFF_WQKVT0 = 0;                                   // [1152][1024] bf16
static constexpr size_t OFF_WQKVT1 = OFF_WQKVT0 + (size_t)1152*1024*2;
static constexpr size_t OFF_WOT    = OFF_WQKVT1 + (size_t)1152*1024*2;    // [1024][1024] bf16 single
static constexpr size_t OFF_W1T    = OFF_WOT    + (size_t)1024*1024*2;    // [E][4096][1024]
static constexpr size_t OFF_W2T    = OFF_W1T    + (size_t)E_*HID_*D_*2;   // [E][1024][4096]
static constexpr size_t OFF_WOWG   = OFF_W2T    + (size_t)E_*HID_*D_*2;   // [1024][8] f32
static constexpr size_t OFF_HF32   = OFF_WOWG   + (size_t)1024*8*4;       // [4096][1024] f32 (h)
static constexpr size_t OFF_H0     = OFF_HF32   + (size_t)M_*D_*4;        // h split0
static constexpr size_t OFF_H1     = OFF_H0     + (size_t)M_*D_*2;        // h split1
static constexpr size_t OFF_H2     = OFF_H1     + (size_t)M_*D_*2;        // h2 bf16
static constexpr size_t OFF_CTL    = OFF_H2     + (size_t)M_*D_*2;        // 128 ints
static constexpr size_t OFF_TEXP   = OFF_CTL    + 512;
static constexpr size_t OFF_TGATE  = OFF_TEXP   + (size_t)M_*2*4;
static constexpr size_t OFF_R2T    = OFF_TGATE  + (size_t)M_*2*4;
static constexpr size_t OFF_T2R    = OFF_R2T    + (size_t)9216*4;
static constexpr size_t OFF_ZROW   = OFF_T2R    + (size_t)M_*2*4;         // 4096 B zeros
static constexpr size_t OFF_BIG    = OFF_ZROW   + 4096;
// attention phase inside BIG:
static constexpr size_t OFF_Q0     = OFF_BIG;                             // [4096][1024] bf16
static constexpr size_t OFF_Q1     = OFF_Q0   + (size_t)M_*D_*2;
static constexpr size_t OFF_KF0    = OFF_Q1   + (size_t)M_*D_*2;          // frag-major K split0: [2*128][2][512] u16
static constexpr size_t OFF_KF1    = OFF_KF0  + (size_t)2*128*2*512*2;
static constexpr size_t OFF_VF0    = OFF_KF1  + (size_t)2*128*2*512*2;    // frag-major V split0: [2*64][4][512] u16
static constexpr size_t OFF_VF1    = OFF_VF0  + (size_t)2*64*4*512*2;
static constexpr size_t OFF_OF32   = OFF_VF1  + (size_t)2*64*4*512*2;     // o fp32 [4096][1024]
static constexpr size_t OFF_AOBF   = OFF_OF32 + (size_t)M_*D_*4;          // o bf16 [4096][1024]
static constexpr size_t OFF_XF32   = OFF_Q0;                              // x2 fp32 (aliases Q0/Q1, safe)
// MoE phase aliases BIG:
static constexpr size_t OFF_TACT   = OFF_BIG;                             // [9216][4096] bf16
static constexpr size_t OFF_CONTR  = OFF_TACT + (size_t)9216*HID_*2;      // [9216][1024] bf16

// ---------------- transposes ----------------
__global__ __launch_bounds__(256) void transpose_split2_k(const float* __restrict__ in,
        u16* __restrict__ o0, u16* __restrict__ o1, int R, int C)
{
    __shared__ float tile[32][33];
    int tx = threadIdx.x & 31, ty = threadIdx.x >> 5;
    int c0 = blockIdx.x * 32, r0 = blockIdx.y * 32;
#pragma unroll
    for (int k = 0; k < 4; ++k)
        tile[ty + k*8][tx] = in[(size_t)(r0 + ty + k*8)*C + c0 + tx];
    __syncthreads();
#pragma unroll
    for (int k = 0; k < 4; ++k) {
        float v = tile[tx][ty + k*8];
        u16 h, m; split2(v, h, m);
        size_t idx = (size_t)(c0 + ty + k*8)*R + r0 + tx;
        o0[idx] = h; o1[idx] = m;
    }
}

__global__ __launch_bounds__(256) void transpose_k(const float* __restrict__ in,
                                                   u16* __restrict__ out, int R, int C)
{
    __shared__ u16 tile[32][33];
    int bz = blockIdx.z;
    in  += (size_t)bz * R * C;
    out += (size_t)bz * R * C;
    int tx = threadIdx.x & 31, ty = threadIdx.x >> 5;
    int c0 = blockIdx.x * 32, r0 = blockIdx.y * 32;
#pragma unroll
    for (int k = 0; k < 4; ++k)
        tile[ty + k*8][tx] = f2b_rne(in[(size_t)(r0 + ty + k*8)*C + c0 + tx]);
    __syncthreads();
#pragma unroll
    for (int k = 0; k < 4; ++k)
        out[(size_t)(c0 + ty + k*8)*R + r0 + tx] = tile[tx][ty + k*8];
}

// ---------------- vectorized 64x64 transpose+convert (W1/W2) ----------------
// float4 loads, ushort8 (16B) stores; padded LDS tile.
__global__ __launch_bounds__(256) void transpose_v_k(const float* __restrict__ in,
                                                     u16* __restrict__ out, int R, int C)
{
    __shared__ u16 tile[64][72];
    int bz = blockIdx.z;
    in  += (size_t)bz * R * C;
    out += (size_t)bz * R * C;
    int c0 = blockIdx.x * 64, r0 = blockIdx.y * 64;
    int tr = threadIdx.x >> 4, tc4 = (threadIdx.x & 15) * 4;
#pragma unroll
    for (int p = 0; p < 4; ++p) {
        float4 v = *(const float4*)(in + (size_t)(r0 + tr + p*16)*C + c0 + tc4);
        tile[tr + p*16][tc4 + 0] = f2b_rne(v.x);
        tile[tr + p*16][tc4 + 1] = f2b_rne(v.y);
        tile[tr + p*16][tc4 + 2] = f2b_rne(v.z);
        tile[tr + p*16][tc4 + 3] = f2b_rne(v.w);
    }
    __syncthreads();
    int orw = threadIdx.x >> 3, occ = (threadIdx.x & 7) * 8;
#pragma unroll
    for (int q = 0; q < 2; ++q) {
        int orow = orw + q*32;                // out row (= in col) within tile
        u16 vals[8];
#pragma unroll
        for (int j = 0; j < 8; ++j) vals[j] = tile[occ + j][orow];
        *(uint4*)(out + (size_t)(c0 + orow)*R + r0 + occ) = *(uint4*)vals;
    }
}

// ---------------- WoWg = Wo @ Wg  (fp32, [1024][8]) ----------------
__global__ __launch_bounds__(64) void wowg_k(const float* __restrict__ Wo,
                                             const float* __restrict__ Wg,
                                             float* __restrict__ wowg)
{
    int i = blockIdx.x, lane = threadIdx.x;
    const float* wr = Wo + (size_t)i*1024;
    float acc[8] = {};
#pragma unroll
    for (int j = 0; j < 16; ++j) {
        int d = j*64 + lane;
        float wv = wr[d];
        const float* g = Wg + (size_t)d*8;
        float4 g0 = *(const float4*)g, g1 = *(const float4*)(g + 4);
        acc[0] += wv*g0.x; acc[1] += wv*g0.y; acc[2] += wv*g0.z; acc[3] += wv*g0.w;
        acc[4] += wv*g1.x; acc[5] += wv*g1.y; acc[6] += wv*g1.z; acc[7] += wv*g1.w;
    }
#pragma unroll
    for (int e = 0; e < 8; ++e)
#pragma unroll
        for (int o = 32; o; o >>= 1) acc[e] += __shfl_down(acc[e], o);
    if (lane == 0) {
#pragma unroll
        for (int e = 0; e < 8; ++e) wowg[i*8 + e] = acc[e];
    }
}

// ---------------- rmsnorm1: x -> h (f32 + 2-split) ----------------
__global__ __launch_bounds__(256) void rmsnorm1_k(const float* __restrict__ x,
                                                  float* __restrict__ hf,
                                                  u16* __restrict__ h0, u16* __restrict__ h1)
{
    int row = blockIdx.x, t = threadIdx.x;
    float4 v = ((const float4*)(x + (size_t)row*1024))[t];
    float ss = v.x*v.x + v.y*v.y + v.z*v.z + v.w*v.w;
#pragma unroll
    for (int o = 32; o; o >>= 1) ss += __shfl_down(ss, o);
    __shared__ float red[4];
    if ((t & 63) == 0) red[t >> 6] = ss;
    __syncthreads();
    float tot = red[0] + red[1] + red[2] + red[3];
    float sc = 32.0f / fmaxf(sqrtf(tot), 1e-12f);
    float vv[4] = {v.x*sc, v.y*sc, v.z*sc, v.w*sc};
    ((float4*)(hf + (size_t)row*1024))[t] = *(float4*)vv;
    u16 a0[4], a1[4];
#pragma unroll
    for (int j = 0; j < 4; ++j) split2(vv[j], a0[j], a1[j]);
    *(uint2*)(h0 + (size_t)row*1024 + t*4) = *(uint2*)a0;
    *(uint2*)(h1 + (size_t)row*1024 + t*4) = *(uint2*)a1;
}

// ---------------- QKV projection: 64x128 tile, A0/A1/B0/B1 staged once, 3 sweeps ----------------
__global__ __launch_bounds__(256) void gemm_qkv(
    const u16* __restrict__ A0, const u16* __restrict__ A1,
    const u16* __restrict__ B0, const u16* __restrict__ B1,
    u16* __restrict__ q0, u16* __restrict__ q1,
    u16* __restrict__ kf0, u16* __restrict__ kf1,
    u16* __restrict__ vf0, u16* __restrict__ vf1)
{
    int rb = blockIdx.x, cb = blockIdx.y;
    __shared__ __attribute__((aligned(16))) char L[24576]; // As0 0 | As1 4K | Bs0 8K | Bs1 16K
    int t = threadIdx.x, w = t >> 6, lane = t & 63, r = lane & 15, g = lane >> 4;
    int wr = w >> 1, wc = w & 1;
    int arow = t >> 2, colA = (t & 3)*8;

    const char* a0c = (const char*)(A0 + (size_t)(rb*64  + arow)*1024 + colA);
    const char* a1c = (const char*)(A1 + (size_t)(rb*64  + arow)*1024 + colA);
    const char* b0c = (const char*)(B0 + (size_t)(cb*128 + arow)*1024 + colA);
    const char* b1c = (const char*)(B1 + (size_t)(cb*128 + arow)*1024 + colA);
    const size_t BH = (size_t)64*1024*2;  // +64 B-rows

    int aoff[2], boff[4];
#pragma unroll
    for (int i = 0; i < 2; ++i) aoff[i] = ((wr*32 + i*16 + r)*32 + g*8)*2;
#pragma unroll
    for (int i = 0; i < 4; ++i) boff[i] = ((wc*64 + i*16 + r)*32 + g*8)*2;

    f32x4 acc[2][4] = {};
    for (int kt = 0; kt < 32; ++kt) {
        __syncthreads();
        gld16(L +          t*16, a0c + kt*64);
        gld16(L + 4096  +  t*16, a1c + kt*64);
        gld16(L + 8192  +  t*16, b0c + kt*64);
        gld16(L + 12288 +  t*16, b0c + BH + kt*64);
        gld16(L + 16384 +  t*16, b1c + kt*64);
        gld16(L + 20480 +  t*16, b1c + BH + kt*64);
        __syncthreads();
        bf16x8 a0v[2], a1v[2], b0v[4], b1v[4];
#pragma unroll
        for (int i = 0; i < 2; ++i) { a0v[i] = *(const bf16x8*)(L + aoff[i]); a1v[i] = *(const bf16x8*)(L + 4096 + aoff[i]); }
#pragma unroll
        for (int i = 0; i < 4; ++i) { b0v[i] = *(const bf16x8*)(L + 8192 + boff[i]); b1v[i] = *(const bf16x8*)(L + 16384 + boff[i]); }
#pragma unroll
        for (int mi = 0; mi < 2; ++mi)
#pragma unroll
            for (int ni = 0; ni < 4; ++ni) {
                acc[mi][ni] = __builtin_amdgcn_mfma_f32_16x16x32_bf16(a0v[mi], b0v[ni], acc[mi][ni], 0, 0, 0);
                acc[mi][ni] = __builtin_amdgcn_mfma_f32_16x16x32_bf16(a0v[mi], b1v[ni], acc[mi][ni], 0, 0, 0);
                acc[mi][ni] = __builtin_amdgcn_mfma_f32_16x16x32_bf16(a1v[mi], b0v[ni], acc[mi][ni], 0, 0, 0);
            }
    }

#pragma unroll
    for (int mi = 0; mi < 2; ++mi)
#pragma unroll
        for (int ni = 0; ni < 4; ++ni) {
            int row0 = rb*64 + wr*32 + mi*16 + g*4;
            int col  = cb*128 + wc*64 + ni*16 + r;
#pragma unroll
            for (int reg = 0; reg < 4; ++reg) {
                float val = acc[mi][ni][reg];
                int rr = row0 + reg;
                if (col < 1024) {           // q, pre-scaled by 1/8
                    u16 hh, mm; split2(val * 0.125f, hh, mm);
                    size_t idx = (size_t)rr*1024 + col;
                    q0[idx] = hh; q1[idx] = mm;
                } else {
                    int c = col - 1024;     // 0..127: k (0-63) | v (64-127)
                    u16 hh, mm; split2(val, hh, mm);
                    int bb = rr >> 11, kv = rr & 2047;
                    if (c < 64) {           // K' [bb*128+ntg][kc][gg*16+r2][j]
                        int ntg = kv >> 4, r2 = kv & 15, kc = c >> 5, gg = (c >> 3) & 3, j = c & 7;
                        size_t off = ((((size_t)bb*128 + ntg)*2 + kc)*64 + gg*16 + r2)*8 + j;
                        kf0[off] = hh; kf1[off] = mm;
                    } else {                // V' [bb*64+kvc][ntg][gg*16+r2][j]
                        int d = c - 64;
                        int ntg = d >> 4, r2 = d & 15, kvc = kv >> 5, gg = (kv >> 3) & 3, j = kv & 7;
                        size_t off = ((((size_t)bb*64 + kvc)*4 + ntg)*64 + gg*16 + r2)*8 + j;
                        vf0[off] = hh; vf1[off] = mm;
                    }
                }
            }
        }
}

// ---------------- flash attention (MQA), 2-split, 4 warps x 16 q-rows (round-4 shape) ----------------
// grid (32 q-tiles of 64, 16 heads, 2 batch); 256 thr; KVBLK=64; LDS 40KB -> 4 blocks/CU.
__global__ __launch_bounds__(256) void attn_k(
    const u16* __restrict__ q0, const u16* __restrict__ q1,
    const u16* __restrict__ kfr0, const u16* __restrict__ kfr1,
    const u16* __restrict__ vfr0, const u16* __restrict__ vfr1,
    float* __restrict__ of32, u16* __restrict__ obf)
{
    int qt = blockIdx.x, h = blockIdx.y, b = blockIdx.z;
    int t = threadIdx.x, w = t >> 6, lane = t & 63, r = lane & 15, g = lane >> 4;
    __shared__ __attribute__((aligned(16))) char smem[40960];
    char* plw = smem + 32768 + w*2048;   // per-warp P buffer [16][64] u16, XOR-swizzled

    const char* K0c = (const char*)kfr0;
    const char* K1c = (const char*)kfr1;
    const char* V0c = (const char*)vfr0;
    const char* V1c = (const char*)vfr1;

    int qrow = b*2048 + qt*64 + w*16 + r;
    bf16x8 qf0[2], qf1[2];
#pragma unroll
    for (int kc = 0; kc < 2; ++kc) {
        size_t qi = (size_t)qrow*1024 + h*64 + kc*32 + g*8;
        qf0[kc] = *(const bf16x8*)(q0 + qi);
        qf1[kc] = *(const bf16x8*)(q1 + qi);
    }

    f32x4 accO[4] = {};
    float mrun[4], lrun[4];
#pragma unroll
    for (int reg = 0; reg < 4; ++reg) { mrun[reg] = -1e30f; lrun[reg] = 0.f; }

    for (int kt = 0; kt < 32; ++kt) {
        __syncthreads();
        {   // stage K (2 splits, 8KB each) + V (2 splits, 8KB each)
            size_t kb = ((size_t)(b*128 + kt*4))*2048;
            gld16(smem +         t*16, K0c + kb + t*16);
            gld16(smem + 4096  + t*16, K0c + kb + 4096 + t*16);
            gld16(smem + 8192  + t*16, K1c + kb + t*16);
            gld16(smem + 12288 + t*16, K1c + kb + 4096 + t*16);
            size_t vb = ((size_t)(b*64 + kt*2))*4096;
            gld16(smem + 16384 + t*16, V0c + vb + t*16);
            gld16(smem + 20480 + t*16, V0c + vb + 4096 + t*16);
            gld16(smem + 24576 + t*16, V1c + vb + t*16);
            gld16(smem + 28672 + t*16, V1c + vb + 4096 + t*16);
        }
        __syncthreads();

        // QK^T: 2-split, 3 products
        f32x4 s[4] = {};
#pragma unroll
        for (int nt = 0; nt < 4; ++nt)
#pragma unroll
            for (int kc = 0; kc < 2; ++kc) {
                bf16x8 kf0 = *(const bf16x8*)(smem + (nt*2 + kc)*1024 + lane*16);
                bf16x8 kf1 = *(const bf16x8*)(smem + 8192 + (nt*2 + kc)*1024 + lane*16);
                s[nt] = __builtin_amdgcn_mfma_f32_16x16x32_bf16(qf0[kc], kf0, s[nt], 0, 0, 0);
                s[nt] = __builtin_amdgcn_mfma_f32_16x16x32_bf16(qf0[kc], kf1, s[nt], 0, 0, 0);
                s[nt] = __builtin_amdgcn_mfma_f32_16x16x32_bf16(qf1[kc], kf0, s[nt], 0, 0, 0);
            }

        // online softmax (per q-row = (g, reg); kv spread over r-lanes)
#pragma unroll
        for (int reg = 0; reg < 4; ++reg) {
            float mx = fmaxf(fmaxf(s[0][reg], s[1][reg]), fmaxf(s[2][reg], s[3][reg]));
#pragma unroll
            for (int d = 1; d < 16; d <<= 1) mx = fmaxf(mx, __shfl_xor(mx, d));
            float mn = fmaxf(mrun[reg], mx);
            float alpha = __expf(mrun[reg] - mn);
            float ls = 0.f;
#pragma unroll
            for (int nt = 0; nt < 4; ++nt) {
                float pv = __expf(s[nt][reg] - mn);
                s[nt][reg] = pv; ls += pv;
            }
#pragma unroll
            for (int d = 1; d < 16; d <<= 1) ls += __shfl_xor(ls, d);
            lrun[reg] = lrun[reg]*alpha + ls;
            mrun[reg] = mn;
#pragma unroll
            for (int nt = 0; nt < 4; ++nt) accO[nt][reg] *= alpha;
        }

        // PV: P 2-split over 2 phases through per-warp swizzled LDS
#pragma unroll
        for (int ps = 0; ps < 2; ++ps) {
#pragma unroll
            for (int nt = 0; nt < 4; ++nt)
#pragma unroll
                for (int reg = 0; reg < 4; ++reg) {
                    float pv = s[nt][reg];
                    u16 hh = f2b_rne(pv);
                    if (ps) hh = f2b_rne(pv - b2f(hh));
                    int gr = g*4 + reg;
                    int off = (gr*128 + (nt*16 + r)*2) ^ ((gr & 7) << 4);
                    *(u16*)(plw + off) = hh;
                }
#pragma unroll
            for (int kc = 0; kc < 2; ++kc) {
                int po = (r*128 + kc*64 + g*16) ^ ((r & 7) << 4);
                bf16x8 pf = *(const bf16x8*)(plw + po);
#pragma unroll
                for (int nt = 0; nt < 4; ++nt) {
                    bf16x8 vf0 = *(const bf16x8*)(smem + 16384 + (kc*4 + nt)*1024 + lane*16);
                    accO[nt] = __builtin_amdgcn_mfma_f32_16x16x32_bf16(pf, vf0, accO[nt], 0, 0, 0);
                    if (ps == 0) {
                        bf16x8 vf1 = *(const bf16x8*)(smem + 24576 + (kc*4 + nt)*1024 + lane*16);
                        accO[nt] = __builtin_amdgcn_mfma_f32_16x16x32_bf16(pf, vf1, accO[nt], 0, 0, 0);
                    }
                }
            }
        }
    }

#pragma unroll
    for (int nt = 0; nt < 4; ++nt)
#pragma unroll
        for (int reg = 0; reg < 4; ++reg) {
            float o = accO[nt][reg] / lrun[reg];
            int row = b*2048 + qt*64 + w*16 + g*4 + reg;
            size_t idx = (size_t)row*1024 + h*64 + nt*16 + r;
            of32[idx] = o;
            obf[idx] = f2b_rne(o);
        }
}

// ---------------- single-bf16 128x128 GEMM (gld16 staging) ----------------
// EP: 0 = fp32 out (val + addsrc)   1 = gelu -> bf16 with packed LDS epilogue
template<int EP, bool MOE, bool INDIR>
__global__ __launch_bounds__(256) void gemm1(
    const u16* __restrict__ Abase, const u16* __restrict__ Bbase,
    u16* __restrict__ outb, float* __restrict__ outf, const float* __restrict__ addsrc,
    const int* __restrict__ r2t, const int* __restrict__ ctl, const u16* __restrict__ zrow,
    int K, int N)
{
    int rb = blockIdx.x, cb = blockIdx.y;
    if (MOE) { if (rb*128 >= ctl[16]) return; }
    const u16* Bt = Bbase;
    if (MOE) Bt += (size_t)ctl[32 + rb] * N * K;

    __shared__ __attribute__((aligned(16))) u16 SM[8192];   // As 8KB | Bs 8KB
    char* As = (char*)SM;
    char* Bs = (char*)SM + 8192;
    int t = threadIdx.x, w = t >> 6, lane = t & 63, r = lane & 15, g = lane >> 4;
    int wr = w >> 1, wc = w & 1;
    int arow0 = t >> 2, colA = (t & 3)*8;

    const char *gA0c, *gA1c;
    if (INDIR) {
        int tk0 = r2t[rb*128 + arow0];
        int tk1 = r2t[rb*128 + 64 + arow0];
        gA0c = (const char*)((tk0 < 0 ? zrow : Abase + (size_t)tk0*K) + colA);
        gA1c = (const char*)((tk1 < 0 ? zrow : Abase + (size_t)tk1*K) + colA);
    } else {
        gA0c = (const char*)(Abase + (size_t)(rb*128 + arow0)*K + colA);
        gA1c = (const char*)(Abase + (size_t)(rb*128 + 64 + arow0)*K + colA);
    }
    const char* gB0c = (const char*)(Bt + (size_t)(cb*128 + arow0)*K + colA);
    const char* gB1c = (const char*)(Bt + (size_t)(cb*128 + 64 + arow0)*K + colA);

    int aoff[4], boff[4];
#pragma unroll
    for (int i = 0; i < 4; ++i) {
        aoff[i] = ((wr*64 + i*16 + r)*32 + g*8)*2;
        boff[i] = ((wc*64 + i*16 + r)*32 + g*8)*2;
    }
    f32x4 acc[4][4] = {};
    int nk = K >> 5;
    for (int kt = 0; kt < nk; ++kt) {
        __syncthreads();
        gld16(As + t*16,        gA0c + kt*64);
        gld16(As + 4096 + t*16, gA1c + kt*64);
        gld16(Bs + t*16,        gB0c + kt*64);
        gld16(Bs + 4096 + t*16, gB1c + kt*64);
        __syncthreads();
        bf16x8 av[4], bv[4];
#pragma unroll
        for (int i = 0; i < 4; ++i) av[i] = *(const bf16x8*)(As + aoff[i]);
#pragma unroll
        for (int i = 0; i < 4; ++i) bv[i] = *(const bf16x8*)(Bs + boff[i]);
#pragma unroll
        for (int mi = 0; mi < 4; ++mi)
#pragma unroll
            for (int ni = 0; ni < 4; ++ni)
                acc[mi][ni] = __builtin_amdgcn_mfma_f32_16x16x32_bf16(av[mi], bv[ni], acc[mi][ni], 0, 0, 0);
    }

    int bm = rb*128, bn = cb*128;
    if (EP == 1) {
        // packed epilogue: gelu -> per-warp LDS (16x72 u16) -> dwordx4 stores
        __syncthreads();                 // As/Bs dead, reuse
        u16* eb = SM + w*1152;           // 16 rows x 72, per warp
#pragma unroll
        for (int mi = 0; mi < 4; ++mi) {
#pragma unroll
            for (int ni = 0; ni < 4; ++ni)
#pragma unroll
                for (int reg = 0; reg < 4; ++reg) {
                    float val = acc[mi][ni][reg];
                    float u  = 1.5957691216f * (val + 0.044715f*val*val*val);
                    eb[(g*4 + reg)*72 + ni*16 + r] = f2b_rne(val / (1.0f + __expf(-u)));
                }
            // per-warp buffer: DS ops in-order per wave, no barrier needed
#pragma unroll
            for (int q = 0; q < 2; ++q) {
                int idx = q*64 + lane;
                int row = idx >> 3, colc = (idx & 7)*8;
                uint4 vv = *(const uint4*)(eb + row*72 + colc);
                *(uint4*)(outb + (size_t)(bm + wr*64 + mi*16 + row)*N + bn + wc*64 + colc) = vv;
            }
        }
    } else {
#pragma unroll
        for (int mi = 0; mi < 4; ++mi)
#pragma unroll
            for (int ni = 0; ni < 4; ++ni) {
                int row0 = bm + wr*64 + mi*16 + g*4;
                int col  = bn + wc*64 + ni*16 + r;
#pragma unroll
                for (int reg = 0; reg < 4; ++reg) {
                    float val = acc[mi][ni][reg];
                    size_t idx = (size_t)(row0 + reg)*N + col;
                    outf[idx] = val + addsrc[idx];
                }
            }
    }
}

// ---------------- MoE GEMM2: 64x128 tile (K=4096, N=1024), packed epilogue ----------------
__global__ __launch_bounds__(256) void gemm_moe2(
    const u16* __restrict__ Abase, const u16* __restrict__ Bbase,
    u16* __restrict__ outb, const int* __restrict__ ctl)
{
    int rb = blockIdx.x, cb = blockIdx.y;
    if (rb*64 >= ctl[16]) return;
    const u16* Bt = Bbase + (size_t)ctl[32 + (rb >> 1)] * (size_t)1024 * 4096;

    __shared__ __attribute__((aligned(16))) char L[12288]; // As 4K | Bs 8K
    int t = threadIdx.x, w = t >> 6, lane = t & 63, r = lane & 15, g = lane >> 4;
    int wr = w >> 1, wc = w & 1;
    int arow = t >> 2, colA = (t & 3)*8;

    const char* aC = (const char*)(Abase + (size_t)(rb*64  + arow)*4096 + colA);
    const char* bC = (const char*)(Bt    + (size_t)(cb*128 + arow)*4096 + colA);
    const size_t BH = (size_t)64*4096*2;

    int aoff[2], boff[4];
#pragma unroll
    for (int i = 0; i < 2; ++i) aoff[i] = ((wr*32 + i*16 + r)*32 + g*8)*2;
#pragma unroll
    for (int i = 0; i < 4; ++i) boff[i] = ((wc*64 + i*16 + r)*32 + g*8)*2;

    f32x4 acc[2][4] = {};
    for (int kt = 0; kt < 128; ++kt) {
        __syncthreads();
        gld16(L +         t*16, aC + kt*64);
        gld16(L + 4096 +  t*16, bC + kt*64);
        gld16(L + 8192 +  t*16, bC + BH + kt*64);
        __syncthreads();
        bf16x8 av[2], bv[4];
#pragma unroll
        for (int i = 0; i < 2; ++i) av[i] = *(const bf16x8*)(L + aoff[i]);
#pragma unroll
        for (int i = 0; i < 4; ++i) bv[i] = *(const bf16x8*)(L + 4096 + boff[i]);
#pragma unroll
        for (int mi = 0; mi < 2; ++mi)
#pragma unroll
            for (int ni = 0; ni < 4; ++ni)
                acc[mi][ni] = __builtin_amdgcn_mfma_f32_16x16x32_bf16(av[mi], bv[ni], acc[mi][ni], 0, 0, 0);
    }

    // packed epilogue
    __syncthreads();
    u16* eb = (u16*)L + w*1152;          // 16 rows x 72, per warp (4*1152*2 = 9216B <= 12288B)
#pragma unroll
    for (int mi = 0; mi < 2; ++mi) {
#pragma unroll
        for (int ni = 0; ni < 4; ++ni)
#pragma unroll
            for (int reg = 0; reg < 4; ++reg)
                eb[(g*4 + reg)*72 + ni*16 + r] = f2b_rne(acc[mi][ni][reg]);
#pragma unroll
        for (int q = 0; q < 2; ++q) {
            int idx = q*64 + lane;
            int row = idx >> 3, colc = (idx & 7)*8;
            uint4 vv = *(const uint4*)(eb + row*72 + colc);
            *(uint4*)(outb + (size_t)(rb*64 + wr*32 + mi*16 + row)*1024 + cb*128 + wc*64 + colc) = vv;
        }
    }
}

// ---------------- fused rmsnorm2 + exact-fp32 top-2 gating (4 tokens/block) ----------------
__global__ __launch_bounds__(256) void gate_k(const float* __restrict__ x2,
                                             const float* __restrict__ hrow,
                                             const float* __restrict__ orow,
                                             const float* __restrict__ Wg,
                                             const float* __restrict__ wowg,
                                             u16* __restrict__ h2,
                                             int* __restrict__ texp, float* __restrict__ tgate,
                                             int* __restrict__ ctl)
{
    int tkn = blockIdx.x*4 + (threadIdx.x >> 6);
    int lane = threadIdx.x & 63;
    const float* xr  = x2   + (size_t)tkn*1024;
    const float* hr  = hrow + (size_t)tkn*1024;
    const float* orp = orow + (size_t)tkn*1024;
    float xv[16];
    float ss = 0.f;
    float acc[8] = {};
#pragma unroll
    for (int j = 0; j < 16; ++j) {
        int d = j*64 + lane;
        float xf = xr[d]; xv[j] = xf; ss += xf*xf;
        float hf = hr[d], of = orp[d];
        const float* wg = Wg + (size_t)d*8;
        const float* wo = wowg + (size_t)d*8;
        float4 a0 = *(const float4*)wg, a1 = *(const float4*)(wg + 4);
        float4 b0 = *(const float4*)wo, b1 = *(const float4*)(wo + 4);
        acc[0] += hf*a0.x + of*b0.x; acc[1] += hf*a0.y + of*b0.y;
        acc[2] += hf*a0.z + of*b0.z; acc[3] += hf*a0.w + of*b0.w;
        acc[4] += hf*a1.x + of*b1.x; acc[5] += hf*a1.y + of*b1.y;
        acc[6] += hf*a1.z + of*b1.z; acc[7] += hf*a1.w + of*b1.w;
    }
#pragma unroll
    for (int o = 32; o; o >>= 1) ss += __shfl_down(ss, o);
    ss = __shfl(ss, 0);
    float sc = 32.0f / fmaxf(sqrtf(ss), 1e-12f);
#pragma unroll
    for (int j = 0; j < 16; ++j)
        h2[(size_t)tkn*1024 + j*64 + lane] = f2b_rne(xv[j]*sc);
#pragma unroll
    for (int e = 0; e < 8; ++e)
#pragma unroll
        for (int o = 32; o; o >>= 1) acc[e] += __shfl_down(acc[e], o);
    if (lane == 0) {
        float lg[8];
#pragma unroll
        for (int e = 0; e < 8; ++e) lg[e] = acc[e]*sc;
        int i0 = 0; float v0 = lg[0];
#pragma unroll
        for (int e = 1; e < 8; ++e) if (lg[e] > v0) { v0 = lg[e]; i0 = e; }
        int i1 = -1; float v1 = -1e30f;
#pragma unroll
        for (int e = 0; e < 8; ++e) if (e != i0 && lg[e] > v1) { v1 = lg[e]; i1 = e; }
        float g0 = 1.0f / (1.0f + __expf(v1 - v0));
        texp[tkn*2] = i0; texp[tkn*2+1] = i1;
        tgate[tkn*2] = g0; tgate[tkn*2+1] = 1.0f - g0;
        atomicAdd(&ctl[i0], 1); atomicAdd(&ctl[i1], 1);
    }
}

// ---------------- MoE plan / assign ----------------
__global__ void plan_k(int* ctl, int* r2t)
{
    if (threadIdx.x == 0) {
        int off = 0;
        for (int e = 0; e < 8; ++e) {
            int c = ctl[e];
            ctl[8 + e] = off;
            int p = (c + 127) & ~127;
            int rb0 = off >> 7, nrbe = p >> 7;
            for (int i = 0; i < nrbe; ++i) ctl[32 + rb0 + i] = e;
            off += p;
        }
        ctl[16] = off; ctl[17] = off >> 7;
    }
    __syncthreads();
    for (int i = threadIdx.x; i < 9216; i += blockDim.x) r2t[i] = -1;
}

__global__ __launch_bounds__(256) void assign_k(const int* __restrict__ texp, int* ctl,
                                                int* __restrict__ r2t, int* __restrict__ t2r)
{
    int tkn = blockIdx.x*256 + threadIdx.x;
    if (tkn >= M_) return;
#pragma unroll
    for (int kk = 0; kk < 2; ++kk) {
        int e = texp[tkn*2 + kk];
        int pos = atomicAdd(&ctl[8 + e], 1);
        r2t[pos] = tkn;
        t2r[tkn*2 + kk] = pos;
    }
}

// ---------------- final combine ----------------
__global__ __launch_bounds__(256) void combine_k(const float* __restrict__ xin,
                                                 const u16* __restrict__ contrib,
                                                 const int* __restrict__ t2r,
                                                 const float* __restrict__ tgate,
                                                 float* __restrict__ out)
{
    int tkn = blockIdx.x;
    int c = threadIdx.x*4;
    int r0 = t2r[tkn*2], r1 = t2r[tkn*2+1];
    float g0 = tgate[tkn*2], g1 = tgate[tkn*2+1];
    float4 sk = *(const float4*)(xin + (size_t)tkn*1024 + c);
    const u16* c0p = contrib + (size_t)r0*1024 + c;
    const u16* c1p = contrib + (size_t)r1*1024 + c;
    float4 o;
    o.x = sk.x + g0*b2f(c0p[0]) + g1*b2f(c1p[0]);
    o.y = sk.y + g0*b2f(c0p[1]) + g1*b2f(c1p[1]);
    o.z = sk.z + g0*b2f(c0p[2]) + g1*b2f(c1p[2]);
    o.w = sk.w + g0*b2f(c0p[3]) + g1*b2f(c1p[3]);
    *(float4*)(out + (size_t)tkn*1024 + c) = o;
}

extern "C" void kernel_launch(void* const* d_in, const int* in_sizes, int n_in,
                              void* d_out, int out_size, void* d_ws, size_t ws_size,
                              hipStream_t stream)
{
    const float* x  = (const float*)d_in[0];
    const float* Wq = (const float*)d_in[1];
    const float* Wk = (const float*)d_in[2];
    const float* Wv = (const float*)d_in[3];
    const float* Wo = (const float*)d_in[4];
    const float* Wg = (const float*)d_in[5];
    const float* W1 = (const float*)d_in[6];
    const float* W2 = (const float*)d_in[7];
    float* out = (float*)d_out;

    char* ws = (char*)d_ws;
    auto U = [&](size_t off) { return (u16*)(ws + off); };
    auto F = [&](size_t off) { return (float*)(ws + off); };
    int*   CTL  = (int*)(ws + OFF_CTL);
    int*   TEXP = (int*)(ws + OFF_TEXP);
    float* TGATE= (float*)(ws + OFF_TGATE);
    int*   R2T  = (int*)(ws + OFF_R2T);
    int*   T2R  = (int*)(ws + OFF_T2R);

    hipMemsetAsync(ws + OFF_CTL,  0, 512,  stream);
    hipMemsetAsync(ws + OFF_ZROW, 0, 4096, stream);

    dim3 tb(256);
    // weights: QKV merged B^T [1152][1024] 2-split; Wo single; experts single (vectorized)
    transpose_split2_k<<<dim3(32, 32), tb, 0, stream>>>(Wq, U(OFF_WQKVT0), U(OFF_WQKVT1), 1024, 1024);
    transpose_split2_k<<<dim3(2, 32),  tb, 0, stream>>>(Wk, U(OFF_WQKVT0) + (size_t)1024*1024, U(OFF_WQKVT1) + (size_t)1024*1024, 1024, 64);
    transpose_split2_k<<<dim3(2, 32),  tb, 0, stream>>>(Wv, U(OFF_WQKVT0) + (size_t)1088*1024, U(OFF_WQKVT1) + (size_t)1088*1024, 1024, 64);
    transpose_k<<<dim3(32, 32, 1), tb, 0, stream>>>(Wo, U(OFF_WOT), 1024, 1024);
    transpose_v_k<<<dim3(64, 16, 8), tb, 0, stream>>>(W1, U(OFF_W1T), 1024, 4096);
    transpose_v_k<<<dim3(16, 64, 8), tb, 0, stream>>>(W2, U(OFF_W2T), 4096, 1024);
    wowg_k<<<1024, 64, 0, stream>>>(Wo, Wg, F(OFF_WOWG));

    rmsnorm1_k<<<M_, 256, 0, stream>>>(x, F(OFF_HF32), U(OFF_H0), U(OFF_H1));

    // QKV projection (q row-major 2-split; k/v fragment-major 2-split)
    gemm_qkv<<<dim3(64, 9), tb, 0, stream>>>(U(OFF_H0), U(OFF_H1),
        U(OFF_WQKVT0), U(OFF_WQKVT1),
        U(OFF_Q0), U(OFF_Q1), U(OFF_KF0), U(OFF_KF1), U(OFF_VF0), U(OFF_VF1));

    attn_k<<<dim3(32, 16, 2), tb, 0, stream>>>(U(OFF_Q0), U(OFF_Q1),
        U(OFF_KF0), U(OFF_KF1), U(OFF_VF0), U(OFF_VF1), F(OFF_OF32), U(OFF_AOBF));

    // x2 = o @ Wo + h  (single-bf16 GEMM, fp32 out; XF32 aliases Q0/Q1 which are dead)
    gemm1<0, false, false><<<dim3(32, 8), tb, 0, stream>>>(U(OFF_AOBF), U(OFF_WOT),
        nullptr, F(OFF_XF32), F(OFF_HF32), nullptr, nullptr, nullptr, 1024, 1024);

    // rmsnorm2 + exact fp32 logits (h@Wg + o@WoWg) + top-2 gate
    gate_k<<<1024, 256, 0, stream>>>(F(OFF_XF32), F(OFF_HF32), F(OFF_OF32), Wg, F(OFF_WOWG),
        U(OFF_H2), TEXP, TGATE, CTL);
    plan_k<<<1, 256, 0, stream>>>(CTL, R2T);
    assign_k<<<16, 256, 0, stream>>>(TEXP, CTL, R2T, T2R);

    // expert GEMMs (top-2 sparse, single bf16)
    gemm1<1, true, true ><<<dim3(72, 32), tb, 0, stream>>>(U(OFF_H2), U(OFF_W1T),
        U(OFF_TACT), nullptr, nullptr, R2T, CTL, U(OFF_ZROW), 1024, 4096);
    gemm_moe2<<<dim3(144, 8), tb, 0, stream>>>(U(OFF_TACT), U(OFF_W2T), U(OFF_CONTR), CTL);

    combine_k<<<M_, 256, 0, stream>>>(x, U(OFF_CONTR), T2R, TGATE, out);
}